// Round 9
// baseline (536.526 us; speedup 1.0000x reference)
//
#include <hip/hip_runtime.h>

#define NNODES 2000
#define BATCH  64
#define DIM    256
#define BLOCK  256
#define MAXGRID 512
#define MAXLVL 128
#define TBLD   264   // transpose-buffer row stride in shorts (pad spreads banks)

typedef __attribute__((ext_vector_type(8))) short  v8s;
typedef __attribute__((ext_vector_type(8))) __bf16 v8bf;
typedef __attribute__((ext_vector_type(4))) float  v4f;
typedef __attribute__((ext_vector_type(4))) int    v4i;

__device__ __forceinline__ short f2bf(float f) {
  unsigned u = __builtin_bit_cast(unsigned, f);
  u += 0x7FFFu + ((u >> 16) & 1u);            // RNE
  return (short)(u >> 16);
}
__device__ __forceinline__ float bf2f(short s) {
  unsigned u = ((unsigned)(unsigned short)s) << 16;
  return __builtin_bit_cast(float, u);
}
__device__ __forceinline__ v4f mfma16(v8s a, v8s b, v4f c) {
  return __builtin_amdgcn_mfma_f32_16x16x32_bf16(
      __builtin_bit_cast(v8bf, a), __builtin_bit_cast(v8bf, b), c, 0, 0, 0);
}
__device__ __forceinline__ float sigmoidf(float x) {
  return __builtin_amdgcn_rcpf(1.0f + __builtin_amdgcn_exp2f(-1.4426950408889634f * x));
}

// prep1: Wt_in[j][k] = bf16(W_in[k][j]); Wt_inner[j][k] = folded W_inner transpose; bar = 0.
__global__ void prep1_kernel(const float* __restrict__ W_in, const float* __restrict__ W_inner,
                             short* __restrict__ Wt_in, short* __restrict__ Wt_inner,
                             int* __restrict__ bar) {
  int idx = blockIdx.x * blockDim.x + threadIdx.x;
  int stride = gridDim.x * blockDim.x;
  for (int i = idx; i < 256 * 256; i += stride) {
    int j = i >> 8, k = i & 255;
    Wt_in[j * 256 + k] = f2bf(W_in[k * 256 + j]);
  }
  for (int i = idx; i < 256 * 512; i += stride) {
    int j = i >> 9, k = i & 511;
    float v = W_inner[(k + 256) * 256 + j];
    if (k < 256) v += W_inner[k * 256 + j];
    Wt_inner[j * 512 + k] = f2bf(v);
  }
  if (idx == 0)
    __hip_atomic_store(bar, 0, __ATOMIC_RELAXED, __HIP_MEMORY_SCOPE_AGENT);
}

// prep2 (1 block): node heights to fixpoint (R3-verified code), bucket nodes by
// height, write order[] / lstart[] / nlev to global for tree_kernel.
__global__ void prep2_kernel(const int* __restrict__ structure,
                             int* __restrict__ order, int* __restrict__ lstart,
                             int* __restrict__ meta) {
  __shared__ int   structS[NNODES * 2];
  __shared__ short h[NNODES];
  __shared__ int   counts[MAXLVL];
  __shared__ int   lsS[MAXLVL + 1];
  __shared__ int   chg, Hlev;
  const int tid = threadIdx.x;
  for (int i = tid; i < NNODES * 2; i += BLOCK) structS[i] = structure[i];
  for (int i = tid; i < NNODES; i += BLOCK) h[i] = 0;
  for (int i = tid; i < MAXLVL; i += BLOCK) counts[i] = 0;
  __syncthreads();
  for (int pass = 0; pass < 4096; ++pass) {
    if (tid == 0) chg = 0;
    __syncthreads();
    int any = 0;
    for (int i = tid; i < NNODES; i += BLOCK) {
      const int s = structS[2 * i];
      if (s >= 0) {
        const int e = structS[2 * i + 1];
        int m = 0;
        for (int c = s; c < e; ++c) m = max(m, (int)h[c]);
        if (m + 1 > (int)h[i]) { h[i] = (short)(m + 1); any = 1; }
      }
    }
    if (any) chg = 1;
    __syncthreads();
    if (chg == 0) break;
    __syncthreads();
  }
  for (int i = tid; i < NNODES; i += BLOCK) atomicAdd(&counts[h[i]], 1);
  __syncthreads();
  if (tid == 0) {
    int acc = 0, hm = 0;
    for (int l = 0; l < MAXLVL; ++l) {
      lsS[l] = acc; acc += counts[l];
      if (counts[l] > 0) hm = l + 1;
    }
    lsS[MAXLVL] = acc;
    Hlev = hm;
    meta[0] = hm;
  }
  __syncthreads();
  for (int i = tid; i <= MAXLVL; i += BLOCK) lstart[i] = lsS[i];
  const int wave = tid >> 6, lane = tid & 63;
  for (int lev = wave; lev < Hlev; lev += 4) {
    int cnt = lsS[lev];
    for (int base = 0; base < NNODES; base += 64) {
      const int i = base + lane;
      const bool p = (i < NNODES) && ((int)h[i] == lev);
      const unsigned long long m = __ballot(p);
      if (p) order[cnt + (int)__popcll(m & ((1ull << lane) - 1ull))] = i;
      cnt += (int)__popcll(m);
    }
  }
}

// Level-synchronous tree evaluation with SOFT barriers (no cache-flush fences).
// R4-R8: per-item cross-block handoff (store-drain -> flag -> poll -> IF loads)
// pinned the wall at ~285us regardless of item size / coalescing / scheduling.
// Here items within a level run back-to-back with ZERO polls, flags, or drains;
// the only sync is one relaxed-atomic barrier per level (~12 total). Cross-level
// data moves via sc0sc1 (coherent at IF; R4-verified), drained once per block per
// level before the barrier arrive. Cooperative launch + occupancy-derived grid
// guarantees co-residency for the soft barrier (R5-verified pattern).
__launch_bounds__(BLOCK, 2)
__global__ void tree_kernel(const int* __restrict__ structure, const float* __restrict__ features,
                            const float* __restrict__ b_in, const float* __restrict__ b_inner,
                            const short* __restrict__ Wt_in, const short* __restrict__ Wt_inner,
                            const int* __restrict__ order, const int* __restrict__ lstart,
                            const int* __restrict__ meta,
                            short* __restrict__ state, int* __restrict__ bar,
                            float* __restrict__ out) {
  // 32 batch rows x 512 k (bf16), XOR-swizzled chunks: phys chunk = (k>>3) ^ (row&7).
  // Reused per item as a [32][TBLD] transpose tile for coalesced stores.
  __shared__ short Xs[32 * 512];   // 32 KiB

  const int tid  = threadIdx.x;
  const int wave = tid >> 6;       // 0..3
  const int lane = tid & 63;
  const int ln15 = lane & 15;
  const int quad = lane >> 4;
  const int rl3  = ln15 & 7;

  const int rowb = tid >> 5;       // 0..7: base row for pooling/stores (row = rowb + 8g)
  const int ch   = tid & 31;       // 16B chunk within a 512B state row

  // j = wave*64 + nt*16 + ln15 is item-invariant: hoist bias loads
  float bia_in[4], bia_nn[4];
  #pragma unroll
  for (int nt = 0; nt < 4; ++nt) {
    const int j = wave * 64 + nt * 16 + ln15;
    bia_in[nt] = b_in[j];
    bia_nn[nt] = b_inner[j];
  }

  const int nlev = meta[0];

  for (int lev = 0; lev < nlev; ++lev) {
    const int kbeg = lstart[lev];
    const int cnt  = lstart[lev + 1] - kbeg;
    for (int idx = (int)blockIdx.x; idx < 2 * cnt; idx += (int)gridDim.x) {
      const int node = order[kbeg + (idx >> 1)];
      const int half = idx & 1;
      const int s = structure[2 * node];
      const int e = structure[2 * node + 1];
      const bool leaf = (s < 0);
      const int nc = e - s;               // 1..4 when inner
      const int K = leaf ? 256 : 512;
      const short* __restrict__ W = leaf ? Wt_in : Wt_inner;

      // ---- build Xs (bf16) for the half's 32 rows (coalesced mapping) ----
      float4 pf[4][2];
      #pragma unroll
      for (int g = 0; g < 4; ++g) {
        const int b = half * 32 + rowb + 8 * g;
        const float* __restrict__ fp = features + ((size_t)b * NNODES + node) * DIM + ch * 8;
        pf[g][0] = ((const float4*)fp)[0];
        pf[g][1] = ((const float4*)fp)[1];
      }
      if (leaf) {
        #pragma unroll
        for (int g = 0; g < 4; ++g) {
          const int row = rowb + 8 * g;       // row & 7 == rowb
          const float4 f0 = pf[g][0], f1 = pf[g][1];
          v8s o;
          o[0] = f2bf(f0.x); o[1] = f2bf(f0.y); o[2] = f2bf(f0.z); o[3] = f2bf(f0.w);
          o[4] = f2bf(f1.x); o[5] = f2bf(f1.y); o[6] = f2bf(f1.z); o[7] = f2bf(f1.w);
          *(v8s*)&Xs[(row << 9) + ((ch ^ rowb) << 3)] = o;
        }
      } else {
        // coalesced child loads: sc0sc1 (bypass stale L1/L2, coherent at IF);
        // one wave64 instruction covers contiguous 512B state rows. One waitcnt.
        v4i cb[4][4];   // [ci][g]
        #pragma unroll
        for (int ci = 0; ci < 4; ++ci) {
          if (ci < nc) {   // block-uniform branch
            #pragma unroll
            for (int g = 0; g < 4; ++g) {
              const short* cp = state +
                  ((size_t)(s + ci) * BATCH + half * 32 + rowb + 8 * g) * DIM + ch * 8;
              asm volatile("global_load_dwordx4 %0, %1, off sc0 sc1"
                           : "=v"(cb[ci][g]) : "v"(cp));
            }
          }
        }
        asm volatile("s_waitcnt vmcnt(0)" ::: "memory");
        __builtin_amdgcn_sched_barrier(0);   // rule #18: pin VALU uses after the wait

        const float inv = 1.0f / (float)(nc + 1);
        #pragma unroll
        for (int g = 0; g < 4; ++g) {
          const int row = rowb + 8 * g;
          const float4 f0 = pf[g][0], f1 = pf[g][1];
          float sm[8] = {f0.x, f0.y, f0.z, f0.w, f1.x, f1.y, f1.z, f1.w};
          float mn[8];
          #pragma unroll
          for (int qq = 0; qq < 8; ++qq) mn[qq] = sm[qq];
          #pragma unroll
          for (int ci = 0; ci < 4; ++ci) {
            if (ci < nc) {
              const v8s cv = __builtin_bit_cast(v8s, cb[ci][g]);
              #pragma unroll
              for (int qq = 0; qq < 8; ++qq) {
                const float v = bf2f(cv[qq]);
                sm[qq] += v; mn[qq] = fminf(mn[qq], v);
              }
            }
          }
          v8s om, on;
          #pragma unroll
          for (int qq = 0; qq < 8; ++qq) { om[qq] = f2bf(sm[qq] * inv); on[qq] = f2bf(mn[qq]); }
          *(v8s*)&Xs[(row << 9) + ((ch ^ rowb) << 3)]        = om;  // c_mean: k in [0,256)
          *(v8s*)&Xs[(row << 9) + (((ch + 32) ^ rowb) << 3)] = on;  // c_min:  k in [256,512)
        }
      }
      __syncthreads();   // Xs ready

      // ---- GEMM: [32 x K] @ Wt^T -> [32 x 256]; 4 waves x 64 cols; W from L2 ----
      v4f acc[2][4];
      #pragma unroll
      for (int mt = 0; mt < 2; ++mt)
        #pragma unroll
        for (int nt = 0; nt < 4; ++nt) acc[mt][nt] = v4f{0.f, 0.f, 0.f, 0.f};

      const short* __restrict__ Wp = W + (size_t)(wave * 64 + ln15) * K + quad * 8;
      const int nkc = K >> 5;
      v8s bcur[4];
      #pragma unroll
      for (int nt = 0; nt < 4; ++nt) bcur[nt] = *(const v8s*)(Wp + (size_t)nt * 16 * K);
      for (int kc = 0; kc < nkc; ++kc) {
        const int kn = (kc + 1 < nkc) ? kc + 1 : kc;   // last iter: harmless re-load
        v8s bnxt[4];
        #pragma unroll
        for (int nt = 0; nt < 4; ++nt) bnxt[nt] = *(const v8s*)(Wp + (size_t)nt * 16 * K + kn * 32);
        v8s af[2];
        #pragma unroll
        for (int mt = 0; mt < 2; ++mt) {
          const int r = mt * 16 + ln15;               // r&7 == rl3
          af[mt] = *(const v8s*)&Xs[(r << 9) + (((kc * 4 + quad) ^ rl3) << 3)];
        }
        #pragma unroll
        for (int mt = 0; mt < 2; ++mt)
          #pragma unroll
          for (int nt = 0; nt < 4; ++nt)
            acc[mt][nt] = mfma16(af[mt], bcur[nt], acc[mt][nt]);
        #pragma unroll
        for (int nt = 0; nt < 4; ++nt) bcur[nt] = bnxt[nt];
      }
      __syncthreads();   // all Xs reads done before transpose-tile overwrite

      // ---- epilogue: bias + sigmoid -> LDS transpose tile [32][TBLD] ----
      #pragma unroll
      for (int nt = 0; nt < 4; ++nt) {
        const int j = wave * 64 + nt * 16 + ln15;
        const float bs = leaf ? bia_in[nt] : bia_nn[nt];
        #pragma unroll
        for (int mt = 0; mt < 2; ++mt) {
          #pragma unroll
          for (int r = 0; r < 4; ++r) {
            const int bb = mt * 16 + quad * 4 + r;   // 0..31 (row within half-slab)
            const float v = sigmoidf(acc[mt][nt][r] + bs);
            Xs[bb * TBLD + j] = f2bf(v);
            if (node == 0) out[(half * 32 + bb) * DIM + j] = v;   // exact fp32, root only
          }
        }
      }
      __syncthreads();   // transpose tile ready

      // ---- coalesced state store: 4 x dwordx4 sc0sc1 per thread (16KB/item) ----
      // NOT drained here -- drained once per block at the level barrier.
      #pragma unroll
      for (int g = 0; g < 4; ++g) {
        const int row = rowb + 8 * g;                // 0..31
        const v4i val = *(const v4i*)&Xs[row * TBLD + ch * 8];
        short* sp = state + ((size_t)node * BATCH + half * 32 + row) * DIM + ch * 8;
        asm volatile("global_store_dwordx4 %0, %1, off sc0 sc1" :: "v"(sp), "v"(val));
      }
      __syncthreads();   // WAR: transpose-tile reads done before next item's build
    } // items of level

    // ---- soft level barrier: drain stores to IF, arrive, spin (no cache flush) ----
    asm volatile("s_waitcnt vmcnt(0)" ::: "memory");
    __syncthreads();
    if (tid == 0) {
      __hip_atomic_fetch_add(bar, 1, __ATOMIC_RELAXED, __HIP_MEMORY_SCOPE_AGENT);
      const int target = (lev + 1) * (int)gridDim.x;
      int g = 0;
      while (__hip_atomic_load(bar, __ATOMIC_RELAXED, __HIP_MEMORY_SCOPE_AGENT) < target &&
             g < (1 << 24)) {
        __builtin_amdgcn_s_sleep(1); ++g;
      }
    }
    __syncthreads();
  } // levels
}

extern "C" void kernel_launch(void* const* d_in, const int* in_sizes, int n_in,
                              void* d_out, int out_size, void* d_ws, size_t ws_size,
                              hipStream_t stream) {
  const int*   structure = (const int*)d_in[0];
  const float* features  = (const float*)d_in[1];
  const float* W_in      = (const float*)d_in[2];
  const float* b_in      = (const float*)d_in[3];
  const float* W_inner   = (const float*)d_in[4];
  const float* b_inner   = (const float*)d_in[5];
  float* out = (float*)d_out;

  char* ws = (char*)d_ws;
  short* state = (short*)ws;                                   // 2000*64*256*2 = 65,536,000 B
  size_t off = (size_t)NNODES * BATCH * DIM * 2;
  short* Wt_in = (short*)(ws + off);    off += 256 * 256 * 2;  // 131,072 B
  short* Wt_inner = (short*)(ws + off); off += 512 * 256 * 2;  // 262,144 B
  int* order  = (int*)(ws + off);       off += NNODES * 4;     // 8,000 B
  int* lstart = (int*)(ws + off);       off += (MAXLVL + 1) * 4;
  int* meta   = (int*)(ws + off);       off += 4;
  int* bar    = (int*)(ws + off);                               // 4 B

  prep1_kernel<<<dim3(256), dim3(256), 0, stream>>>(W_in, W_inner, Wt_in, Wt_inner, bar);
  prep2_kernel<<<dim3(1), dim3(BLOCK), 0, stream>>>(structure, order, lstart, meta);

  // Cooperative capacity: never launch more blocks than are co-resident (R1/R5 lesson).
  static int coop_grid = 0;
  if (coop_grid == 0) {
    int nb = 0;
    hipError_t err = hipOccupancyMaxActiveBlocksPerMultiprocessor(
        &nb, reinterpret_cast<const void*>(tree_kernel), BLOCK, 0);
    if (err != hipSuccess || nb < 1) nb = 1;
    long g = (long)nb * 256;
    if (g > MAXGRID) g = MAXGRID;
    coop_grid = (int)g;
  }

  void* args[12];
  args[0]  = (void*)&structure;
  args[1]  = (void*)&features;
  args[2]  = (void*)&b_in;
  args[3]  = (void*)&b_inner;
  args[4]  = (void*)&Wt_in;
  args[5]  = (void*)&Wt_inner;
  args[6]  = (void*)&order;
  args[7]  = (void*)&lstart;
  args[8]  = (void*)&meta;
  args[9]  = (void*)&state;
  args[10] = (void*)&bar;
  args[11] = (void*)&out;
  hipLaunchCooperativeKernel((void*)tree_kernel, dim3(coop_grid), dim3(BLOCK), args, 0, stream);
}